// Round 6
// baseline (254.216 us; speedup 1.0000x reference)
//
#include <hip/hip_runtime.h>
#include <math.h>

// MoE gate: B=4, S=4096, H=2048, E=64, top-2, seq_aux loss.
// d_out layout (float): topk_idx [16384*2] | topk_weight [16384*2] | aux_loss [1]
//
// K1 gemm_partial: barrier-free streaming MFMA GEMM. Wave = 16 tokens x 64
//    experts x K-quarter; A direct from global (per-lane fragment loads),
//    bf16 hi/lo split in-register (3-term, err <= ~1e-5); B from L2-resident
//    pre-packed fragments. 4 waves/SIMD hide latency; no LDS, no barriers.
//    Writes 4 partial-logit planes.
// K2 gate_topk: wave-per-token; sums 4 partials, softmax/top-4/aux; flags
//    tokens with fp32 gap < TAU into a worklist.
// K3 rerank_exact: fp64 re-rank of flagged tokens only (~2-4%).

#define TT 16384
#define HH 2048
#define EE 64
#define BB 4
#define TAU 2e-3f  // gap threshold: >> 100x the bf16-split logit error bound
#define NREP 8     // atomic replication for aux accumulators

typedef float v4f __attribute__((ext_vector_type(4)));
typedef float f4v __attribute__((ext_vector_type(4)));
typedef short s8v __attribute__((ext_vector_type(8)));

__device__ __forceinline__ unsigned short f2bf(float f) {
    unsigned u = __float_as_uint(f);
    return (unsigned short)((u + 0x7fffu + ((u >> 16) & 1u)) >> 16);
}
__device__ __forceinline__ float bf2f(unsigned short h) {
    return __uint_as_float(((unsigned)h) << 16);
}

// Pre-pack W[E][H] into MFMA B-fragment order, bf16 hi/lo:
// b[nt][ks64][lane][j] = w[nt*16 + (lane&15)][ks64*32 + (lane>>4)*8 + j]
__global__ void prep_b(const float* __restrict__ w,
                       unsigned short* __restrict__ bhi,
                       unsigned short* __restrict__ blo) {
    int idx = blockIdx.x * blockDim.x + threadIdx.x;   // 0..131071
    int j    = idx & 7;
    int lane = (idx >> 3) & 63;
    int ks   = (idx >> 9) & 63;
    int nt   = idx >> 15;
    int e = nt * 16 + (lane & 15);
    int k = ks * 32 + (lane >> 4) * 8 + j;
    float f = w[e * HH + k];
    unsigned short h = f2bf(f);
    bhi[idx] = h;
    blo[idx] = f2bf(f - bf2f(h));
}

// ---------------- K1: streaming MFMA GEMM -> 4 partial planes ----------------
__global__ __launch_bounds__(256, 4) void gemm_partial(
    const float* __restrict__ x,
    const unsigned short* __restrict__ bhi, const unsigned short* __restrict__ blo,
    float* __restrict__ plog) {

    const int tid  = threadIdx.x;
    const int kseg = tid >> 6;                 // wave = K-quarter 0..3
    const int lane = tid & 63;
    const int tok0 = blockIdx.x * 16;

    // A-fragment source: lane covers row (lane&15), k-base (lane>>4)*8
    const float* __restrict__ xr =
        x + (size_t)(tok0 + (lane & 15)) * HH + kseg * 512 + (lane >> 4) * 8;
    const int ks0 = kseg * 16;                 // first 32-k slice index (of 64)

    f4v acc[4];
#pragma unroll
    for (int nt = 0; nt < 4; ++nt) acc[nt] = (f4v){0.f, 0.f, 0.f, 0.f};

    // prime the 1-deep pipeline (slice 0)
    v4f a0 = *(const v4f*)xr;
    v4f a1 = *(const v4f*)(xr + 4);
    s8v bh[4], bl[4];
#pragma unroll
    for (int nt = 0; nt < 4; ++nt) {
        const size_t off = ((size_t)(nt * 64 + ks0) * 64 + lane) * 8;
        bh[nt] = *(const s8v*)&bhi[off];
        bl[nt] = *(const s8v*)&blo[off];
    }

#pragma unroll
    for (int ks = 0; ks < 16; ++ks) {
        v4f na0, na1;
        s8v nbh[4], nbl[4];
        if (ks < 15) {                         // prefetch slice ks+1
            na0 = *(const v4f*)(xr + (ks + 1) * 32);
            na1 = *(const v4f*)(xr + (ks + 1) * 32 + 4);
#pragma unroll
            for (int nt = 0; nt < 4; ++nt) {
                const size_t off = ((size_t)(nt * 64 + ks0 + ks + 1) * 64 + lane) * 8;
                nbh[nt] = *(const s8v*)&bhi[off];
                nbl[nt] = *(const s8v*)&blo[off];
            }
        }
        // convert current A slice to bf16 hi/lo
        float xs[8] = {a0.x, a0.y, a0.z, a0.w, a1.x, a1.y, a1.z, a1.w};
        s8v ah, al;
#pragma unroll
        for (int j = 0; j < 8; ++j) {
            unsigned short h = f2bf(xs[j]);
            ah[j] = (short)h;
            al[j] = (short)f2bf(xs[j] - bf2f(h));
        }
#pragma unroll
        for (int nt = 0; nt < 4; ++nt) {
            acc[nt] = __builtin_amdgcn_mfma_f32_16x16x32_bf16(ah, bh[nt], acc[nt], 0, 0, 0);
            acc[nt] = __builtin_amdgcn_mfma_f32_16x16x32_bf16(ah, bl[nt], acc[nt], 0, 0, 0);
            acc[nt] = __builtin_amdgcn_mfma_f32_16x16x32_bf16(al, bh[nt], acc[nt], 0, 0, 0);
        }
        a0 = na0; a1 = na1;
#pragma unroll
        for (int nt = 0; nt < 4; ++nt) { bh[nt] = nbh[nt]; bl[nt] = nbl[nt]; }
    }

    // C-layout: col = lane&15, row = (lane>>4)*4 + r
    float* __restrict__ pout = plog + (size_t)kseg * TT * EE;
#pragma unroll
    for (int nt = 0; nt < 4; ++nt)
#pragma unroll
        for (int r = 0; r < 4; ++r)
            pout[(size_t)(tok0 + (lane >> 4) * 4 + r) * EE + nt * 16 + (lane & 15)] =
                acc[nt][r];
}

// ---------------- K2: wave-per-token topk/softmax/aux + flag ----------------
__global__ __launch_bounds__(256) void gate_topk(
    const float* __restrict__ plog,
    float* __restrict__ out_idx, float* __restrict__ out_w,
    float* __restrict__ g_cnt, float* __restrict__ g_ssum,
    int* __restrict__ wl_cnt, int* __restrict__ wl) {

    __shared__ float bssum[EE];
    const int tid  = threadIdx.x;
    const int lane = tid & 63;
    const int t    = blockIdx.x * 4 + (tid >> 6);
    const int rep  = (blockIdx.x & (NREP - 1)) * (BB * EE);

    if (tid < EE) bssum[tid] = 0.f;

    const size_t o = (size_t)t * EE + lane;
    float l = plog[o] + plog[(size_t)TT * EE + o] +
              plog[2 * (size_t)TT * EE + o] + plog[3 * (size_t)TT * EE + o];

    // softmax score (fp32, feeds aux only)
    float mx = l;
#pragma unroll
    for (int off = 32; off; off >>= 1) mx = fmaxf(mx, __shfl_xor(mx, off, 64));
    float p = __expf(l - mx);
    float Z = p;
#pragma unroll
    for (int off = 32; off; off >>= 1) Z += __shfl_xor(Z, off, 64);
    float s = p / Z;

    // top-4 by fp32 logit (tie -> lower index)
    float v = l;
    int cand[4]; float cl[4];
#pragma unroll
    for (int r = 0; r < 4; ++r) {
        float bv = v; int bi = lane;
#pragma unroll
        for (int off = 32; off; off >>= 1) {
            float ov = __shfl_xor(bv, off, 64);
            int   oi = __shfl_xor(bi, off, 64);
            if (ov > bv || (ov == bv && oi < bi)) { bv = ov; bi = oi; }
        }
        cand[r] = bi; cl[r] = bv;
        if (lane == bi) v = -3.4e38f;
    }

    __syncthreads();
    atomicAdd(&bssum[lane], s);

    if (lane == 0) {
        const int b = t >> 12;
        atomicAdd(&g_cnt[rep + b * EE + cand[0]], 1.f);
        atomicAdd(&g_cnt[rep + b * EE + cand[1]], 1.f);
        float w1 = 1.f / (1.f + __expf(cl[1] - cl[0]));  // softmax denom cancels
        out_idx[t * 2]     = (float)cand[0];
        out_idx[t * 2 + 1] = (float)cand[1];
        out_w[t * 2]       = w1;
        out_w[t * 2 + 1]   = 1.f - w1;
        if (cl[0] - cl[1] < TAU || cl[1] - cl[2] < TAU) {
            int pos = atomicAdd(wl_cnt, 1);
            wl[pos] = t;
        }
    }

    __syncthreads();
    if (tid < EE) {
        const int b0 = (blockIdx.x * 4) >> 12;  // block-uniform batch
        atomicAdd(&g_ssum[rep + b0 * EE + tid], bssum[tid]);
    }
}

// ---------------- K3: fp64 exact re-rank of flagged tokens ----------------
__global__ __launch_bounds__(256) void rerank_exact(
    const float* __restrict__ plog, const float* __restrict__ x,
    const float* __restrict__ w,
    const int* __restrict__ wl_cnt, const int* __restrict__ wl,
    float* __restrict__ out_idx, float* __restrict__ out_w) {

    const int lane = threadIdx.x & 63;
    const int wid  = blockIdx.x * 4 + (threadIdx.x >> 6);
    const int n    = wl_cnt[0];

    for (int i = wid; i < n; i += 32 * 4) {
        const int t = wl[i];
        const size_t o = (size_t)t * EE + lane;
        float l = plog[o] + plog[(size_t)TT * EE + o] +
                  plog[2 * (size_t)TT * EE + o] + plog[3 * (size_t)TT * EE + o];

        float v = l;
        int cand[4];
#pragma unroll
        for (int r = 0; r < 4; ++r) {
            float bv = v; int bi = lane;
#pragma unroll
            for (int off = 32; off; off >>= 1) {
                float ov = __shfl_xor(bv, off, 64);
                int   oi = __shfl_xor(bi, off, 64);
                if (ov > bv || (ov == bv && oi < bi)) { bv = ov; bi = oi; }
            }
            cand[r] = bi;
            if (lane == bi) v = -3.4e38f;
        }

        const float* __restrict__ xt  = x + (size_t)t * HH;
        const float* __restrict__ w0p = w + (size_t)cand[0] * HH;
        const float* __restrict__ w1p = w + (size_t)cand[1] * HH;
        const float* __restrict__ w2p = w + (size_t)cand[2] * HH;
        const float* __restrict__ w3p = w + (size_t)cand[3] * HH;
        double d0 = 0.0, d1 = 0.0, d2 = 0.0, d3 = 0.0;
#pragma unroll
        for (int ii = 0; ii < 8; ++ii) {
            const int k = ii * 256 + lane * 4;
            v4f xv = *(const v4f*)(xt + k);
            v4f a0 = *(const v4f*)(w0p + k);
            v4f a1 = *(const v4f*)(w1p + k);
            v4f a2 = *(const v4f*)(w2p + k);
            v4f a3 = *(const v4f*)(w3p + k);
            double dx0 = (double)xv.x, dx1 = (double)xv.y;
            double dx2 = (double)xv.z, dx3 = (double)xv.w;
            d0 = fma(dx0, (double)a0.x, d0); d0 = fma(dx1, (double)a0.y, d0);
            d0 = fma(dx2, (double)a0.z, d0); d0 = fma(dx3, (double)a0.w, d0);
            d1 = fma(dx0, (double)a1.x, d1); d1 = fma(dx1, (double)a1.y, d1);
            d1 = fma(dx2, (double)a1.z, d1); d1 = fma(dx3, (double)a1.w, d1);
            d2 = fma(dx0, (double)a2.x, d2); d2 = fma(dx1, (double)a2.y, d2);
            d2 = fma(dx2, (double)a2.z, d2); d2 = fma(dx3, (double)a2.w, d2);
            d3 = fma(dx0, (double)a3.x, d3); d3 = fma(dx1, (double)a3.y, d3);
            d3 = fma(dx2, (double)a3.z, d3); d3 = fma(dx3, (double)a3.w, d3);
        }
#pragma unroll
        for (int off = 32; off; off >>= 1) {
            d0 += __shfl_xor(d0, off, 64);
            d1 += __shfl_xor(d1, off, 64);
            d2 += __shfl_xor(d2, off, 64);
            d3 += __shfl_xor(d3, off, 64);
        }

        double bd[4] = {d0, d1, d2, d3};
        int e1 = cand[0]; double l1 = bd[0];
#pragma unroll
        for (int r = 1; r < 4; ++r)
            if (bd[r] > l1 || (bd[r] == l1 && cand[r] < e1)) { l1 = bd[r]; e1 = cand[r]; }
        int e2 = -1; double l2 = -1e300;
#pragma unroll
        for (int r = 0; r < 4; ++r) {
            if (cand[r] == e1) continue;
            if (e2 < 0 || bd[r] > l2 || (bd[r] == l2 && cand[r] < e2)) { l2 = bd[r]; e2 = cand[r]; }
        }

        double w1 = 1.0 / (1.0 + exp(l2 - l1));
        if (lane == 0) {
            out_idx[t * 2]     = (float)e1;
            out_idx[t * 2 + 1] = (float)e2;
            out_w[t * 2]       = (float)w1;
            out_w[t * 2 + 1]   = (float)(1.0 - w1);
        }
    }
}

// aux = 0.01/(B * 128 * S) * sum_{b,e} cnt[b,e]*ssum[b,e]   (E/(S*K)=1/128)
__global__ void finalize(const float* __restrict__ g_cnt,
                         const float* __restrict__ g_ssum,
                         float* __restrict__ aux_out) {
    int lane = threadIdx.x;  // 64 threads, lane = expert
    float a = 0.f;
    for (int b = 0; b < BB; ++b) {
        float c = 0.f, ss = 0.f;
#pragma unroll
        for (int r = 0; r < NREP; ++r) {
            c  += g_cnt[r * (BB * EE) + b * EE + lane];
            ss += g_ssum[r * (BB * EE) + b * EE + lane];
        }
        a += c * ss;
    }
#pragma unroll
    for (int off = 32; off; off >>= 1) a += __shfl_xor(a, off, 64);
    if (lane == 0) aux_out[0] = a * (0.01f / (4.f * 128.f * 4096.f));
}

extern "C" void kernel_launch(void* const* d_in, const int* in_sizes, int n_in,
                              void* d_out, int out_size, void* d_ws, size_t ws_size,
                              hipStream_t stream) {
    const float* x = (const float*)d_in[0];   // [4,4096,2048]
    const float* w = (const float*)d_in[1];   // [64,2048]
    float* out = (float*)d_out;
    float* out_idx = out;                 // [16384*2]
    float* out_w   = out + 2 * TT;        // [16384*2]
    float* aux     = out + 4 * TT;        // [1]

    // ws layout
    float* plog = (float*)d_ws;                                     // 16 MB (4 planes)
    unsigned short* bhi = (unsigned short*)(plog + 4 * (size_t)TT * EE); // 256 KB
    unsigned short* blo = bhi + (size_t)EE * HH;                    // 256 KB
    float* g_cnt  = (float*)(blo + (size_t)EE * HH);                // 8 KB
    float* g_ssum = g_cnt + NREP * BB * EE;                         // 8 KB
    int*   wl_cnt = (int*)(g_ssum + NREP * BB * EE);                // 64 B
    int*   wl     = wl_cnt + 16;                                    // 64 KB

    hipMemsetAsync(g_cnt, 0, (2 * NREP * BB * EE + 16) * sizeof(float), stream);
    prep_b<<<(EE * HH) / 256, 256, 0, stream>>>(w, bhi, blo);
    gemm_partial<<<TT / 16, 256, 0, stream>>>(x, bhi, blo, plog);
    gate_topk<<<TT / 4, 256, 0, stream>>>(plog, out_idx, out_w,
                                          g_cnt, g_ssum, wl_cnt, wl);
    rerank_exact<<<32, 256, 0, stream>>>(plog, x, w, wl_cnt, wl, out_idx, out_w);
    finalize<<<1, 64, 0, stream>>>(g_cnt, g_ssum, aux);
}

// Round 7
// 249.801 us; speedup vs baseline: 1.0177x; 1.0177x over previous
//
#include <hip/hip_runtime.h>
#include <math.h>

// MoE gate: B=4, S=4096, H=2048, E=64, top-2, seq_aux loss.
// d_out layout (float): topk_idx [16384*2] | topk_weight [16384*2] | aux_loss [1]
//
// TWO dispatches only (launch overhead dominated the previous 6-dispatch plan):
// K0 prep_b: pack W into MFMA B-frag bf16 hi/lo (RNE); block 0 zeroes accums.
// K1 moe_mega: per block = 16 tokens.
//    Phase A: barrier-free K-split streaming MFMA GEMM (wave = K-quarter),
//             A trunc-split fp32->bf16 hi/lo in-register (err ~1e-4 worst,
//             TAU=3e-3 gap test covers ordering), partials -> LDS.
//    Phase B: wave = 4 tokens: softmax/aux, top-4, gap test; flagged waves
//             (~5%) do inline fp64 re-rank (exact top-2 + weights).
//    Phase C: block aux atomics -> ticket -> last block computes aux_loss.

#define TT 16384
#define HH 2048
#define EE 64
#define BB 4
#define TAU 3e-3f
#define NREP 8
#define NBLK (TT / 16)

typedef float v4f __attribute__((ext_vector_type(4)));
typedef float f4v __attribute__((ext_vector_type(4)));
typedef short s8v __attribute__((ext_vector_type(8)));

__device__ __forceinline__ unsigned short f2bf_rne(float f) {
    unsigned u = __float_as_uint(f);
    return (unsigned short)((u + 0x7fffu + ((u >> 16) & 1u)) >> 16);
}
__device__ __forceinline__ float bf2f(unsigned short h) {
    return __uint_as_float(((unsigned)h) << 16);
}

// K0: pack W[E][H] -> MFMA B-frag order, bf16 hi/lo (RNE):
// b[nt][ks][lane][j] = w[nt*16 + (lane&15)][ks*32 + (lane>>4)*8 + j]
// Block 0 additionally zeroes g_cnt/g_ssum/ticket (removes a memset dispatch).
__global__ void prep_b(const float* __restrict__ w,
                       unsigned short* __restrict__ bhi,
                       unsigned short* __restrict__ blo,
                       float* __restrict__ gz) {
    int idx = blockIdx.x * blockDim.x + threadIdx.x;   // 0..131071
    int j    = idx & 7;
    int lane = (idx >> 3) & 63;
    int ks   = (idx >> 9) & 63;
    int nt   = idx >> 15;
    int e = nt * 16 + (lane & 15);
    int k = ks * 32 + (lane >> 4) * 8 + j;
    float f = w[e * HH + k];
    unsigned short h = f2bf_rne(f);
    bhi[idx] = h;
    blo[idx] = f2bf_rne(f - bf2f(h));
    if (blockIdx.x == 0)
        for (int i = threadIdx.x; i < 2 * NREP * BB * EE + 16; i += 256)
            gz[i] = 0.f;
}

// ---------------- K1: fused GEMM + gate + aux ----------------
__global__ __launch_bounds__(256, 3) void moe_mega(
    const float* __restrict__ x, const float* __restrict__ w,
    const unsigned short* __restrict__ bhi, const unsigned short* __restrict__ blo,
    float* __restrict__ out_idx, float* __restrict__ out_w,
    float* __restrict__ aux_out,
    float* __restrict__ g_cnt, float* __restrict__ g_ssum,
    int* __restrict__ ticket) {

    __shared__ float part[4][16][EE];   // 16 KB partial logits
    __shared__ float bssum[EE];
    __shared__ float bcnt[EE];
    __shared__ int lastflag;

    const int tid  = threadIdx.x;
    const int kseg = tid >> 6;                 // wave = K-quarter 0..3
    const int lane = tid & 63;
    const int tok0 = blockIdx.x * 16;
    const int b    = tok0 >> 12;               // batch (uniform: 16 | 4096)

    if (tid < EE) { bssum[tid] = 0.f; bcnt[tid] = 0.f; }

    // ---------- phase A: streaming K-split MFMA GEMM ----------
    const float* __restrict__ xr =
        x + (size_t)(tok0 + (lane & 15)) * HH + kseg * 512 + (lane >> 4) * 8;
    const int ks0 = kseg * 16;

    f4v acc[4];
#pragma unroll
    for (int nt = 0; nt < 4; ++nt) acc[nt] = (f4v){0.f, 0.f, 0.f, 0.f};

    v4f a0 = *(const v4f*)xr;
    v4f a1 = *(const v4f*)(xr + 4);
    s8v bh[4], bl[4];
#pragma unroll
    for (int nt = 0; nt < 4; ++nt) {
        const size_t off = ((size_t)(nt * 64 + ks0) * 64 + lane) * 8;
        bh[nt] = *(const s8v*)&bhi[off];
        bl[nt] = *(const s8v*)&blo[off];
    }

#pragma unroll
    for (int ks = 0; ks < 16; ++ks) {
        v4f na0, na1;
        s8v nbh[4], nbl[4];
        if (ks < 15) {                         // prefetch slice ks+1
            na0 = *(const v4f*)(xr + (ks + 1) * 32);
            na1 = *(const v4f*)(xr + (ks + 1) * 32 + 4);
#pragma unroll
            for (int nt = 0; nt < 4; ++nt) {
                const size_t off = ((size_t)(nt * 64 + ks0 + ks + 1) * 64 + lane) * 8;
                nbh[nt] = *(const s8v*)&bhi[off];
                nbl[nt] = *(const s8v*)&blo[off];
            }
        }
        // truncation split: x = hi + lo exactly at fp32; both bf16 by trunc.
        float xs[8] = {a0.x, a0.y, a0.z, a0.w, a1.x, a1.y, a1.z, a1.w};
        s8v ah, al;
#pragma unroll
        for (int j = 0; j < 8; ++j) {
            unsigned u = __float_as_uint(xs[j]);
            ah[j] = (short)(u >> 16);
            float hif = __uint_as_float(u & 0xffff0000u);
            al[j] = (short)(__float_as_uint(xs[j] - hif) >> 16);
        }
#pragma unroll
        for (int nt = 0; nt < 4; ++nt) {
            acc[nt] = __builtin_amdgcn_mfma_f32_16x16x32_bf16(ah, bh[nt], acc[nt], 0, 0, 0);
            acc[nt] = __builtin_amdgcn_mfma_f32_16x16x32_bf16(ah, bl[nt], acc[nt], 0, 0, 0);
            acc[nt] = __builtin_amdgcn_mfma_f32_16x16x32_bf16(al, bh[nt], acc[nt], 0, 0, 0);
        }
        if (ks < 15) {
            a0 = na0; a1 = na1;
#pragma unroll
            for (int nt = 0; nt < 4; ++nt) { bh[nt] = nbh[nt]; bl[nt] = nbl[nt]; }
        }
    }

    // C-layout: col = lane&15, row = (lane>>4)*4 + r
#pragma unroll
    for (int nt = 0; nt < 4; ++nt)
#pragma unroll
        for (int r = 0; r < 4; ++r)
            part[kseg][(lane >> 4) * 4 + r][nt * 16 + (lane & 15)] = acc[nt][r];
    __syncthreads();

    // ---------- phase B: wave = 4 tokens: softmax/top-4/gate/rerank ----------
    for (int ti = 0; ti < 4; ++ti) {
        const int t = kseg * 4 + ti;
        float l = part[0][t][lane] + part[1][t][lane] +
                  part[2][t][lane] + part[3][t][lane];

        // softmax score (fp32, feeds aux only)
        float mx = l;
#pragma unroll
        for (int off = 32; off; off >>= 1) mx = fmaxf(mx, __shfl_xor(mx, off, 64));
        float p = __expf(l - mx);
        float Z = p;
#pragma unroll
        for (int off = 32; off; off >>= 1) Z += __shfl_xor(Z, off, 64);
        atomicAdd(&bssum[lane], p / Z);

        // top-4 by fp32 logit (tie -> lower index); cl/cand wave-uniform after
        float v = l;
        int cand[4]; float cl[4];
#pragma unroll
        for (int r = 0; r < 4; ++r) {
            float bv = v; int bi = lane;
#pragma unroll
            for (int off = 32; off; off >>= 1) {
                float ov = __shfl_xor(bv, off, 64);
                int   oi = __shfl_xor(bi, off, 64);
                if (ov > bv || (ov == bv && oi < bi)) { bv = ov; bi = oi; }
            }
            cand[r] = bi; cl[r] = bv;
            if (lane == bi) v = -3.4e38f;
        }

        const bool flag = (cl[0] - cl[1] < TAU) || (cl[1] - cl[2] < TAU);
        const int gt = tok0 + t;

        if (lane == 0) {
            atomicAdd(&bcnt[cand[0]], 1.f);
            atomicAdd(&bcnt[cand[1]], 1.f);
        }

        if (!flag) {
            if (lane == 0) {
                float w1 = 1.f / (1.f + __expf(cl[1] - cl[0]));
                out_idx[gt * 2]     = (float)cand[0];
                out_idx[gt * 2 + 1] = (float)cand[1];
                out_w[gt * 2]       = w1;
                out_w[gt * 2 + 1]   = 1.f - w1;
            }
        } else {
            // inline fp64 exact re-rank of the 4 candidates (wave-uniform branch)
            const float* __restrict__ xt  = x + (size_t)gt * HH;
            const float* __restrict__ w0p = w + (size_t)cand[0] * HH;
            const float* __restrict__ w1p = w + (size_t)cand[1] * HH;
            const float* __restrict__ w2p = w + (size_t)cand[2] * HH;
            const float* __restrict__ w3p = w + (size_t)cand[3] * HH;
            double d0 = 0.0, d1 = 0.0, d2 = 0.0, d3 = 0.0;
#pragma unroll 2
            for (int ii = 0; ii < 8; ++ii) {
                const int k = ii * 256 + lane * 4;
                v4f xv = *(const v4f*)(xt + k);
                v4f q0 = *(const v4f*)(w0p + k);
                v4f q1 = *(const v4f*)(w1p + k);
                v4f q2 = *(const v4f*)(w2p + k);
                v4f q3 = *(const v4f*)(w3p + k);
                double dx0 = (double)xv.x, dx1 = (double)xv.y;
                double dx2 = (double)xv.z, dx3 = (double)xv.w;
                d0 = fma(dx0, (double)q0.x, d0); d0 = fma(dx1, (double)q0.y, d0);
                d0 = fma(dx2, (double)q0.z, d0); d0 = fma(dx3, (double)q0.w, d0);
                d1 = fma(dx0, (double)q1.x, d1); d1 = fma(dx1, (double)q1.y, d1);
                d1 = fma(dx2, (double)q1.z, d1); d1 = fma(dx3, (double)q1.w, d1);
                d2 = fma(dx0, (double)q2.x, d2); d2 = fma(dx1, (double)q2.y, d2);
                d2 = fma(dx2, (double)q2.z, d2); d2 = fma(dx3, (double)q2.w, d2);
                d3 = fma(dx0, (double)q3.x, d3); d3 = fma(dx1, (double)q3.y, d3);
                d3 = fma(dx2, (double)q3.z, d3); d3 = fma(dx3, (double)q3.w, d3);
            }
#pragma unroll
            for (int off = 32; off; off >>= 1) {
                d0 += __shfl_xor(d0, off, 64);
                d1 += __shfl_xor(d1, off, 64);
                d2 += __shfl_xor(d2, off, 64);
                d3 += __shfl_xor(d3, off, 64);
            }
            double bd[4] = {d0, d1, d2, d3};
            int e1 = cand[0]; double l1 = bd[0];
#pragma unroll
            for (int r = 1; r < 4; ++r)
                if (bd[r] > l1 || (bd[r] == l1 && cand[r] < e1)) { l1 = bd[r]; e1 = cand[r]; }
            int e2 = -1; double l2 = -1e300;
#pragma unroll
            for (int r = 0; r < 4; ++r) {
                if (cand[r] == e1) continue;
                if (e2 < 0 || bd[r] > l2 || (bd[r] == l2 && cand[r] < e2)) { l2 = bd[r]; e2 = cand[r]; }
            }
            double w1 = 1.0 / (1.0 + exp(l2 - l1));
            if (lane == 0) {
                out_idx[gt * 2]     = (float)e1;
                out_idx[gt * 2 + 1] = (float)e2;
                out_w[gt * 2]       = (float)w1;
                out_w[gt * 2 + 1]   = (float)(1.0 - w1);
            }
        }
    }

    // ---------- phase C: aux accumulate + last-block finalize ----------
    __syncthreads();
    const int rep = (blockIdx.x & (NREP - 1)) * (BB * EE);
    if (tid < EE) {
        atomicAdd(&g_ssum[rep + b * EE + tid], bssum[tid]);
        atomicAdd(&g_cnt[rep + b * EE + tid], bcnt[tid]);
        __threadfence();                       // atomics visible before ticket
    }
    __syncthreads();
    if (tid == 0) lastflag = (atomicAdd(ticket, 1) == NBLK - 1);
    __syncthreads();
    if (lastflag && tid < EE) {
        float a = 0.f;
        for (int bb = 0; bb < BB; ++bb) {
            float c = 0.f, ss = 0.f;
#pragma unroll
            for (int r = 0; r < NREP; ++r) {
                c  += atomicAdd(&g_cnt[r * (BB * EE) + bb * EE + tid], 0.f);
                ss += atomicAdd(&g_ssum[r * (BB * EE) + bb * EE + tid], 0.f);
            }
            a += c * ss;
        }
#pragma unroll
        for (int off = 32; off; off >>= 1) a += __shfl_xor(a, off, 64);
        if (tid == 0) aux_out[0] = a * (0.01f / (4.f * 128.f * 4096.f));
    }
}

extern "C" void kernel_launch(void* const* d_in, const int* in_sizes, int n_in,
                              void* d_out, int out_size, void* d_ws, size_t ws_size,
                              hipStream_t stream) {
    const float* x = (const float*)d_in[0];   // [4,4096,2048]
    const float* w = (const float*)d_in[1];   // [64,2048]
    float* out = (float*)d_out;
    float* out_idx = out;                 // [16384*2]
    float* out_w   = out + 2 * TT;        // [16384*2]
    float* aux     = out + 4 * TT;        // [1]

    // ws layout
    unsigned short* bhi = (unsigned short*)d_ws;                    // 256 KB
    unsigned short* blo = bhi + (size_t)EE * HH;                    // 256 KB
    float* g_cnt  = (float*)(blo + (size_t)EE * HH);                // 8 KB
    float* g_ssum = g_cnt + NREP * BB * EE;                         // 8 KB
    int*   ticket = (int*)(g_ssum + NREP * BB * EE);                // 64 B

    prep_b<<<(EE * HH) / 256, 256, 0, stream>>>(w, bhi, blo, g_cnt);
    moe_mega<<<NBLK, 256, 0, stream>>>(x, w, bhi, blo, out_idx, out_w, aux,
                                       g_cnt, g_ssum, ticket);
}